// Round 1
// baseline (916.845 us; speedup 1.0000x reference)
//
#include <hip/hip_runtime.h>

// Problem constants (from reference): N=1e6 nodes, DIM=128, B=2048 graphs.
#define DIM 128

// -------- Kernel 1: segment-sum pool ------------------------------------
// segment_ids is SORTED, so block b binary-searches its contiguous node
// range [start,end) and sums h[start:end, :] into pool[b, :].
// 128 threads = 4 groups x 32 lanes; each group handles full 128-dim rows
// via float4 (32 lanes x 16B = 512B/node), groups stride over nodes.
__global__ __launch_bounds__(128) void pool_kernel(
    const float* __restrict__ h, const int* __restrict__ seg,
    float* __restrict__ pool, int N) {
  const int b = blockIdx.x;

  // lower_bound(seg, b)
  int lo = 0, hi = N;
  while (lo < hi) { int mid = (lo + hi) >> 1; if (seg[mid] < b) lo = mid + 1; else hi = mid; }
  const int start = lo;
  // lower_bound(seg, b+1)
  hi = N;
  while (lo < hi) { int mid = (lo + hi) >> 1; if (seg[mid] < b + 1) lo = mid + 1; else hi = mid; }
  const int end = lo;

  const int group = threadIdx.x >> 5;   // 0..3
  const int lane  = threadIdx.x & 31;   // 0..31

  float4 acc = make_float4(0.f, 0.f, 0.f, 0.f);
  for (int n = start + group; n < end; n += 4) {
    float4 v = *(const float4*)(h + (size_t)n * DIM + lane * 4);
    acc.x += v.x; acc.y += v.y; acc.z += v.z; acc.w += v.w;
  }

  __shared__ float4 smem[4][32];
  smem[group][lane] = acc;
  __syncthreads();
  if (group == 0) {
    float4 a0 = smem[0][lane], a1 = smem[1][lane], a2 = smem[2][lane], a3 = smem[3][lane];
    float4 r;
    r.x = (a0.x + a1.x) + (a2.x + a3.x);
    r.y = (a0.y + a1.y) + (a2.y + a3.y);
    r.z = (a0.z + a1.z) + (a2.z + a3.z);
    r.w = (a0.w + a1.w) + (a2.w + a3.w);
    *(float4*)(pool + (size_t)b * DIM + lane * 4) = r;
  }
}

// -------- Kernel 2: FC layer + residual on virtual node ------------------
// vn_out[row] = vn_h[row] + relu((vn_h[row] + pool[row]) @ W.T + bias)
// One block per row; x staged in LDS; thread j computes output dim j via
// a float4 dot over W row j (W is 64KB -> L2-resident after first blocks).
__global__ __launch_bounds__(128) void fc_kernel(
    const float* __restrict__ vn_h, const float* __restrict__ pool,
    const float* __restrict__ W, const float* __restrict__ bias,
    float* __restrict__ vn_out) {
  const int row = blockIdx.x;
  const int j = threadIdx.x;

  __shared__ float x[DIM];
  const float vh = vn_h[(size_t)row * DIM + j];
  x[j] = vh + pool[(size_t)row * DIM + j];
  __syncthreads();

  const float4* Wr = (const float4*)(W + (size_t)j * DIM);
  float acc = 0.f;
#pragma unroll
  for (int k = 0; k < DIM / 4; k++) {
    float4 w = Wr[k];
    acc += w.x * x[4 * k + 0] + w.y * x[4 * k + 1] +
           w.z * x[4 * k + 2] + w.w * x[4 * k + 3];
  }
  float t = fmaxf(acc + bias[j], 0.f);
  vn_out[(size_t)row * DIM + j] = vh + t;
}

// -------- Kernel 3: broadcast virtual node back + residual ---------------
// h_out[n,:] = h[n,:] + vn_new[seg[n],:], one float4 per thread.
// Sorted seg -> consecutive nodes hit the same vn_new lines (L1-resident).
__global__ __launch_bounds__(256) void bcast_kernel(
    const float* __restrict__ h, const float* __restrict__ vn_new,
    const int* __restrict__ seg, float* __restrict__ h_out, long total_vec) {
  long idx = (long)blockIdx.x * blockDim.x + threadIdx.x;
  const long stride = (long)gridDim.x * blockDim.x;
  for (; idx < total_vec; idx += stride) {
    const int node = (int)(idx >> 5);        // DIM/4 = 32 float4 per node
    const int v    = (int)(idx & 31);
    const int s    = seg[node];
    float4 hv = ((const float4*)h)[idx];
    float4 vv = ((const float4*)vn_new)[(size_t)s * 32 + v];
    hv.x += vv.x; hv.y += vv.y; hv.z += vv.z; hv.w += vv.w;
    ((float4*)h_out)[idx] = hv;
  }
}

extern "C" void kernel_launch(void* const* d_in, const int* in_sizes, int n_in,
                              void* d_out, int out_size, void* d_ws, size_t ws_size,
                              hipStream_t stream) {
  const float* h    = (const float*)d_in[0];   // [N, DIM]
  const float* vn_h = (const float*)d_in[1];   // [B, DIM]
  const float* W    = (const float*)d_in[2];   // [DIM, DIM]
  const float* bias = (const float*)d_in[3];   // [DIM]
  const int*   seg  = (const int*)d_in[4];     // [N], sorted
  const int N = in_sizes[4];
  const int B = in_sizes[1] / DIM;

  float* vn_out = (float*)d_out;                        // [B, DIM]
  float* h_out  = (float*)d_out + (size_t)B * DIM;      // [N, DIM]
  float* pool   = (float*)d_ws;                         // [B, DIM] scratch

  pool_kernel<<<B, 128, 0, stream>>>(h, seg, pool, N);
  fc_kernel<<<B, DIM, 0, stream>>>(vn_h, pool, W, bias, vn_out);

  const long total_vec = (long)N * (DIM / 4);
  const int blocks = (int)((total_vec + 255) / 256);
  bcast_kernel<<<blocks, 256, 0, stream>>>(h, vn_out, seg, h_out, total_vec);
}